// Round 16
// baseline (272.612 us; speedup 1.0000x reference)
//
#include <hip/hip_runtime.h>
#include <hip/hip_fp16.h>

#define N_NODES 50000
#define N_EDGES 800000
#define IN_F    128
#define HID_F   64
#define OUT_F   40

#define EPB   4096                          // edges per sort block
#define NBLK  ((N_EDGES + EPB - 1) / EPB)   // 196 sort blocks
#define NBK   ((N_NODES + 255) / 256)       // 196 buckets (dst >> 8)
#define CAP   6144                          // per-bucket LDS cap (avg 4082, sd 64)
#define NREP  32                            // BN-stat atomic replicas
#define NB_MM ((N_NODES + 63) / 64)         // 782 gemm2 blocks (64 rows each)
#define NB_G1 ((N_NODES + 127) / 128)       // 391 gemm1 blocks (128 rows each)
#define NB_AG ((N_NODES + 31) / 32)         // 1563 agg blocks (32 rows each)

typedef _Float16 half8v __attribute__((ext_vector_type(8)));
typedef float    f32x4  __attribute__((ext_vector_type(4)));

union h8cv { uint4 u; __half h[8]; };

// ============ dispatch 1: binscatter ONLY (196 blocks) ============
// Stores blkcnt AND colpre_g so k_mid's bucket role needs no O(b) prefix loop.

__global__ __launch_bounds__(512) void k_bin(const int* __restrict__ ei,
                                             int* __restrict__ blkcnt,
                                             int* __restrict__ colpre_g,
                                             unsigned int* __restrict__ bket,
                                             float* __restrict__ st2) {
    __shared__ unsigned int staged[EPB];   // 16 KB
    __shared__ int h[256], fill[256];
    __shared__ int wt[4];
    int t = threadIdx.x;
    int lane = t & 63, wv = t >> 6;
    if (t < 256) h[t] = 0;
    if (blockIdx.x == 0)                   // zero BN-stat replicas once
        for (int i = t; i < NREP * 2 * HID_F; i += 512) st2[i] = 0.f;
    __syncthreads();
    int base = blockIdx.x * EPB;
    int nedge = N_EDGES - base; if (nedge > EPB) nedge = EPB;
#pragma unroll
    for (int it = 0; it < EPB / 512; ++it) {
        int e = base + it * 512 + t;
        if (e < N_EDGES) atomicAdd(&h[ei[N_EDGES + e] >> 8], 1);
    }
    __syncthreads();
    // wave shfl scan over h[256] -> exclusive prefix in fill
    int v = (t < 256) ? h[t] : 0;
    int sv = v;
    if (t < 256) {
#pragma unroll
        for (int o = 1; o < 64; o <<= 1) {
            int u = __shfl_up(sv, o);
            if (lane >= o) sv += u;
        }
        if (lane == 63) wt[wv] = sv;
    }
    __syncthreads();
    if (t < 256) {
        int off = 0;
        if (wv > 0) off += wt[0];
        if (wv > 1) off += wt[1];
        if (wv > 2) off += wt[2];
        int ex = sv + off - v;             // exclusive prefix over buckets
        fill[t] = ex;
        if (t < NBK) colpre_g[t * NBLK + blockIdx.x] = ex;   // per-bucket column offset
    }
    __syncthreads();
#pragma unroll
    for (int it = 0; it < EPB / 512; ++it) {
        int e = base + it * 512 + t;
        if (e < N_EDGES) {
            int srcv = ei[e], dstv = ei[N_EDGES + e];
            int p = atomicAdd(&fill[dstv >> 8], 1);
            staged[p] = ((unsigned int)dstv << 16) | (unsigned int)srcv;
        }
    }
    __syncthreads();
    for (int i = t; i < nedge; i += 512) bket[base + i] = staged[i];
    if (t < NBK) blkcnt[t * NBLK + blockIdx.x] = h[t];
}

// ============ dispatch 2: bucket CSR build (blocks 0..195) || gemm1 (rest) ============

__global__ __launch_bounds__(512) void k_mid(const int* __restrict__ blkcnt,
                                             const int* __restrict__ colpre_g,
                                             const unsigned int* __restrict__ bket,
                                             int* __restrict__ rowptr,
                                             float* __restrict__ dinv,
                                             unsigned short* __restrict__ ssrc,
                                             int* __restrict__ perm,
                                             const float* __restrict__ x,
                                             const float* __restrict__ W1,
                                             __half* __restrict__ h1r) {
    __shared__ uint4 pool[3328];           // 53248 B shared pool (both roles)
    __shared__ int colpre[256], rowcnt[256], boffs[256];
    __shared__ int cnt[256], fillb[256];
    __shared__ int wt[4], wsum[8], sbase, ssize;
    __shared__ int dbin[64], dfl[64];
    int t = threadIdx.x;
    int lane = t & 63, wid = t >> 6;

    if (blockIdx.x < NBK) {
        // ---------------- bucket role ----------------
        unsigned int*   keys = (unsigned int*)pool;                    // 24576 B
        unsigned short* outb = (unsigned short*)((char*)pool + 24576); // 12288 B
        int b = blockIdx.x;

        int cp = 0, rc = 0;
        if (t < NBLK) {
            cp = colpre_g[b * NBLK + t];   // one coalesced load (was O(b) loop)
            rc = blkcnt[b * NBLK + t];
        }
        if (t < 256) { colpre[t] = cp; rowcnt[t] = rc; }
        int red = cp;
#pragma unroll
        for (int o = 32; o > 0; o >>= 1) red += __shfl_down(red, o);
        if (lane == 0) wsum[wid] = red;
        int sv = rc;
        if (t < 256) {
#pragma unroll
            for (int o = 1; o < 64; o <<= 1) {
                int u = __shfl_up(sv, o);
                if (lane >= o) sv += u;
            }
            if (lane == 63) wt[wid] = sv;
        }
        __syncthreads();
        if (t == 0) {
            int s = 0;
#pragma unroll
            for (int r = 0; r < 8; ++r) s += wsum[r];
            sbase = s;
        }
        if (t < 256) {
            int off = 0;
            if (wid > 0) off += wt[0];
            if (wid > 1) off += wt[1];
            if (wid > 2) off += wt[2];
            boffs[t] = sv + off - rc;
            if (t == 255) ssize = sv + off;
        }
        __syncthreads();
        int base = sbase, size = ssize;

        // 32-lane half-wave per segment: 2x segment streams, better lane use
        int hw = t >> 5, hl = t & 31;      // hw 0..15
        for (int jj = hw; jj < NBLK; jj += 16) {
            int len = rowcnt[jj];
            int gs  = jj * EPB + colpre[jj];
            int d0  = boffs[jj];
            for (int o = hl; o < len; o += 32) keys[d0 + o] = bket[gs + o];
        }
        if (t < 256) cnt[t] = 0;
        __syncthreads();

        for (int i = t; i < size; i += 512) atomicAdd(&cnt[(keys[i] >> 16) & 255], 1);
        __syncthreads();
        int cv = (t < 256) ? cnt[t] : 0;
        int sv2 = cv;
        if (t < 256) {
#pragma unroll
            for (int o = 1; o < 64; o <<= 1) {
                int u = __shfl_up(sv2, o);
                if (lane >= o) sv2 += u;
            }
            if (lane == 63) wt[wid] = sv2;
        }
        __syncthreads();
        if (t < 256) {
            int off = 0;
            if (wid > 0) off += wt[0];
            if (wid > 1) off += wt[1];
            if (wid > 2) off += wt[2];
            int ex = sv2 + off - cv;
            fillb[t] = ex;
            int node = b * 256 + t;
            if (node < N_NODES) {
                rowptr[node] = base + ex;
                dinv[node]   = rsqrtf((float)cv + 1.0f);   // + self-loop
            }
        }
        if (b == 0 && t == 0) rowptr[N_NODES] = N_EDGES;
        __syncthreads();

        for (int i = t; i < size; i += 512) {
            unsigned int k = keys[i];
            int p = atomicAdd(&fillb[(k >> 16) & 255], 1);
            outb[p] = (unsigned short)(k & 0xFFFFu);
        }
        __syncthreads();
        for (int i = t; i < size; i += 512) ssrc[base + i] = outb[i];

        // ---- degree-sort this bucket's 256 slots -> perm ----
        if (t < 64) dbin[t] = 0;
        __syncthreads();
        int node2 = b * 256 + t;
        int dg = 63;
        if (t < 256) {
            if (node2 < N_NODES) { dg = cv; if (dg > 62) dg = 62; }
            atomicAdd(&dbin[dg], 1);
        }
        __syncthreads();
        if (t < 64) {                       // one full wave: exclusive scan of 64 bins
            int bv = dbin[t];
            int s = bv;
#pragma unroll
            for (int o = 1; o < 64; o <<= 1) {
                int u = __shfl_up(s, o);
                if (lane >= o) s += u;
            }
            dfl[t] = s - bv;                // exclusive
        }
        __syncthreads();
        if (t < 256) {
            int r = atomicAdd(&dfl[dg], 1);
            perm[b * 256 + r] = node2;      // invalid ids sort last
        }
        return;
    }

    // ---------------- gemm1 role: 128 rows, MFMA 16x16x32 f16 ----------------
    _Float16 (*sA)[IN_F + 8] = (_Float16(*)[IN_F + 8])pool;                    // 34816 B
    _Float16 (*sB)[IN_F + 8] = (_Float16(*)[IN_F + 8])((char*)pool + 34816);   // 17408 B
    int bid = blockIdx.x - NBK;
    int row0 = bid * 128;
    for (int i = t; i < 128 * 32; i += 512) {
        int r  = i >> 5;
        int c4 = i & 31;
        int gr = row0 + r;
        float4 v = make_float4(0.f, 0.f, 0.f, 0.f);
        if (gr < N_NODES) v = ((const float4*)x)[gr * 32 + c4];
        sA[r][c4 * 4 + 0] = (_Float16)v.x;
        sA[r][c4 * 4 + 1] = (_Float16)v.y;
        sA[r][c4 * 4 + 2] = (_Float16)v.z;
        sA[r][c4 * 4 + 3] = (_Float16)v.w;
    }
    for (int i = t; i < IN_F * HID_F; i += 512) {
        int k = i >> 6, n = i & 63;
        sB[n][k] = (_Float16)W1[i];
    }
    __syncthreads();

    int quad = lane >> 4, l15 = lane & 15;
    int m0 = wid * 16;
    half8v af[4];
#pragma unroll
    for (int ks = 0; ks < 4; ++ks)
        af[ks] = *(const half8v*)&sA[m0 + l15][ks * 32 + quad * 8];
    f32x4 acc[4];
#pragma unroll
    for (int nt = 0; nt < 4; ++nt) acc[nt] = (f32x4)(0.f);
#pragma unroll
    for (int nt = 0; nt < 4; ++nt) {
#pragma unroll
        for (int ks = 0; ks < 4; ++ks) {
            half8v bf = *(const half8v*)&sB[nt * 16 + l15][ks * 32 + quad * 8];
            acc[nt] = __builtin_amdgcn_mfma_f32_16x16x32_f16(af[ks], bf, acc[nt], 0, 0, 0);
        }
    }
    int rbase = row0 + m0 + quad * 4;
#pragma unroll
    for (int nt = 0; nt < 4; ++nt) {
        int col = nt * 16 + l15;
#pragma unroll
        for (int r = 0; r < 4; ++r) {
            int gr = rbase + r;
            if (gr < N_NODES)
                h1r[gr * HID_F + col] = __float2half(acc[nt][r]);   // unscaled
        }
    }
}

// ============ dispatch 3: layer-1 aggregation + BN stats ============
// ONE 8-LANE GROUP PER ROW via perm. Single 8-DEEP gather batch per chunk
// (one memory round-trip) — fits the 64-VGPR budget at LB(256,8): measured
// VGPR_Count was 32, so the extra 4x uint4 batch registers fit without
// occupancy loss (R13's idea minus R13's occupancy cost).

__global__ __launch_bounds__(256, 8) void k_agg1(const int* __restrict__ rowptr,
                                                 const unsigned short* __restrict__ ssrc,
                                                 const float* __restrict__ dinv,
                                                 const __half* __restrict__ h1r,
                                                 const float* __restrict__ b1,
                                                 const int* __restrict__ perm,
                                                 __half* __restrict__ agg1h,
                                                 float* __restrict__ st2) {
    __shared__ float vs[32][HID_F + 1];    // 8448 B staged vals for BN reduce
    int t = threadIdx.x;
    int lane = t & 63, wid = t >> 6;
    int g = lane >> 3, i = lane & 7;
    int rloc = wid * 8 + g;                // 0..31
    int d = perm[blockIdx.x * 32 + rloc];  // degree-sorted row id
    bool valid = d < N_NODES;
    int base = 0, end = 0;
    if (valid) { base = rowptr[d]; end = rowptr[d + 1]; }
    float acc[8];
#pragma unroll
    for (int c = 0; c < 8; ++c) acc[c] = 0.f;

    for (int cc = base; cc < end; cc += 8) {
        int nrem = end - cc; if (nrem > 8) nrem = 8;
        int e = 0; float dv_own = 0.f;
        if (i < nrem) {
            e = (int)ssrc[cc + i];
            dv_own = dinv[e];              // own-edge weight, issued early
        }
        uint4 v[8]; float w[8];
#pragma unroll
        for (int k = 0; k < 8; ++k) {      // issue ALL 8 gathers back-to-back
            int sk = __shfl(e,      (lane & 56) + k);
            w[k]   = __shfl(dv_own, (lane & 56) + k);
            if (k < nrem)                  // group-uniform
                v[k] = ((const uint4*)(h1r + (size_t)sk * HID_F))[i];
            else v[k] = make_uint4(0, 0, 0, 0);
        }
#pragma unroll
        for (int k = 0; k < 8; ++k) {
            float wk = (k < nrem) ? w[k] : 0.f;
            h8cv cv; cv.u = v[k];
#pragma unroll
            for (int c = 0; c < 8; ++c)
                acc[c] += wk * __half2float(cv.h[c]);
        }
    }

    float val[8];
    if (valid) {
        float di = dinv[d];
        h8cv self; self.u = ((const uint4*)(h1r + (size_t)d * HID_F))[i];
        const float4 b1a = ((const float4*)b1)[i * 2];
        const float4 b1b = ((const float4*)b1)[i * 2 + 1];
        val[0] = (acc[0] + di * __half2float(self.h[0])) * di + b1a.x;
        val[1] = (acc[1] + di * __half2float(self.h[1])) * di + b1a.y;
        val[2] = (acc[2] + di * __half2float(self.h[2])) * di + b1a.z;
        val[3] = (acc[3] + di * __half2float(self.h[3])) * di + b1a.w;
        val[4] = (acc[4] + di * __half2float(self.h[4])) * di + b1b.x;
        val[5] = (acc[5] + di * __half2float(self.h[5])) * di + b1b.y;
        val[6] = (acc[6] + di * __half2float(self.h[6])) * di + b1b.z;
        val[7] = (acc[7] + di * __half2float(self.h[7])) * di + b1b.w;
        h8cv ov;
#pragma unroll
        for (int c = 0; c < 8; ++c) ov.h[c] = __float2half(val[c]);
        ((uint4*)(agg1h + (size_t)d * HID_F))[i] = ov.u;
    } else {
#pragma unroll
        for (int c = 0; c < 8; ++c) val[c] = 0.f;
    }
#pragma unroll
    for (int c = 0; c < 8; ++c) vs[rloc][i * 8 + c] = val[c];
    __syncthreads();
    if (t < HID_F) {
        float sm = 0.f, s2 = 0.f;
#pragma unroll 4
        for (int r = 0; r < 32; ++r) {
            float v2 = vs[r][t];
            sm += v2; s2 += v2 * v2;
        }
        float* strow = st2 + (blockIdx.x & (NREP - 1)) * (2 * HID_F);
        atomicAdd(&strow[t], sm);
        atomicAdd(&strow[HID_F + t], s2);
    }
}

// ============ dispatch 4: GEMM2 (MFMA), h2p[N,40] pre-scaled by dinv ============

__global__ __launch_bounds__(256) void k_gemm2(const __half* __restrict__ agg1h,
                                               const float* __restrict__ st2,
                                               const float* __restrict__ gamma,
                                               const float* __restrict__ beta,
                                               const float* __restrict__ W2,
                                               const float* __restrict__ dinv,
                                               __half* __restrict__ h2p) {
    __shared__ _Float16 sA[64][HID_F + 8];   // 9216 B
    __shared__ _Float16 sB[48][HID_F + 8];   // 6912 B  (sB[n][k] = W2[k][n], pad n>=40)
    __shared__ float sScale[HID_F], sShift[HID_F];
    int t = threadIdx.x;
    if (t < HID_F) {
        float sm = 0.f, s2 = 0.f;
#pragma unroll
        for (int r = 0; r < NREP; ++r) {
            sm += st2[r * (2 * HID_F) + t];
            s2 += st2[r * (2 * HID_F) + HID_F + t];
        }
        float mean = sm * (1.0f / N_NODES);
        float var  = s2 * (1.0f / N_NODES) - mean * mean;
        float inv  = rsqrtf(var + 1e-5f);
        float gv   = gamma[t];
        sScale[t]  = gv * inv;
        sShift[t]  = beta[t] - gv * inv * mean;
    }
    for (int i = t; i < 48 * HID_F; i += 256) {
        int k = i / 48, n = i - k * 48;
        sB[n][k] = (n < OUT_F) ? (_Float16)W2[k * OUT_F + n] : (_Float16)0.f;
    }
    __syncthreads();
    int row0 = blockIdx.x * 64;
    for (int i = t; i < 64 * HID_F; i += 256) {
        int r = i >> 6, k = i & 63;
        int gr = row0 + r;
        float v = 0.f;
        if (gr < N_NODES) {
            float a = __half2float(agg1h[gr * HID_F + k]);
            v = fmaxf(a * sScale[k] + sShift[k], 0.f);
        }
        sA[r][k] = (_Float16)v;
    }
    __syncthreads();

    int lane = t & 63, wid = t >> 6;
    int quad = lane >> 4, l15 = lane & 15;
    int m0 = wid * 16;
    half8v af[2];
#pragma unroll
    for (int ks = 0; ks < 2; ++ks)
        af[ks] = *(const half8v*)&sA[m0 + l15][ks * 32 + quad * 8];
    f32x4 acc[3];
#pragma unroll
    for (int nt = 0; nt < 3; ++nt) acc[nt] = (f32x4)(0.f);
#pragma unroll
    for (int nt = 0; nt < 3; ++nt) {
#pragma unroll
        for (int ks = 0; ks < 2; ++ks) {
            half8v bf = *(const half8v*)&sB[nt * 16 + l15][ks * 32 + quad * 8];
            acc[nt] = __builtin_amdgcn_mfma_f32_16x16x32_f16(af[ks], bf, acc[nt], 0, 0, 0);
        }
    }
    float dv[4];
    int rbase = row0 + m0 + quad * 4;
#pragma unroll
    for (int r = 0; r < 4; ++r)
        dv[r] = (rbase + r < N_NODES) ? dinv[rbase + r] : 0.f;
#pragma unroll
    for (int nt = 0; nt < 3; ++nt) {
        int col = nt * 16 + l15;
        if (col < OUT_F) {
#pragma unroll
            for (int r = 0; r < 4; ++r) {
                int gr = rbase + r;
                if (gr < N_NODES)
                    h2p[(size_t)gr * OUT_F + col] = __float2half(acc[nt][r] * dv[r]);
            }
        }
    }
}

// ============ dispatch 5: layer-2 aggregation -> d_out ============
// ONE 8-LANE GROUP PER ROW via perm; single 8-deep gather batch at LB(256,8);
// lanes i<5 gather (80 B rows), all lanes shuffle.

__global__ __launch_bounds__(256, 8) void k_agg2(const int* __restrict__ rowptr,
                                                 const unsigned short* __restrict__ ssrc,
                                                 const float* __restrict__ dinv,
                                                 const __half* __restrict__ h2p,
                                                 const float* __restrict__ b2,
                                                 const int* __restrict__ perm,
                                                 float* __restrict__ out) {
    int t = threadIdx.x;
    int lane = t & 63, wid = t >> 6;
    int g = lane >> 3, i = lane & 7;
    int rloc = wid * 8 + g;
    int d = perm[blockIdx.x * 32 + rloc];  // degree-sorted row id
    bool valid = d < N_NODES;
    int base = 0, end = 0;
    if (valid) { base = rowptr[d]; end = rowptr[d + 1]; }
    float acc[8];
#pragma unroll
    for (int c = 0; c < 8; ++c) acc[c] = 0.f;

    for (int cc = base; cc < end; cc += 8) {
        int nrem = end - cc; if (nrem > 8) nrem = 8;
        int e = (i < nrem) ? (int)ssrc[cc + i] : 0;
        int sk[8];
#pragma unroll
        for (int k = 0; k < 8; ++k)
            sk[k] = __shfl(e, (lane & 56) + k);        // all lanes shuffle
        if (i < 5) {
            uint4 v[8];
#pragma unroll
            for (int k = 0; k < 8; ++k) {              // issue ALL 8 gathers
                if (k < nrem)
                    v[k] = ((const uint4*)(h2p + (size_t)sk[k] * OUT_F))[i];
                else v[k] = make_uint4(0, 0, 0, 0);
            }
#pragma unroll
            for (int k = 0; k < 8; ++k) {
                h8cv cv; cv.u = v[k];
#pragma unroll
                for (int c = 0; c < 8; ++c)
                    acc[c] += __half2float(cv.h[c]);
            }
        }
    }

    if (valid && i < 5) {
        h8cv self; self.u = ((const uint4*)(h2p + (size_t)d * OUT_F))[i];
        float di = dinv[d];
        const float4 b2a = ((const float4*)b2)[i * 2];
        const float4 b2b = ((const float4*)b2)[i * 2 + 1];
        float4 o0, o1;
        o0.x = (acc[0] + __half2float(self.h[0])) * di + b2a.x;
        o0.y = (acc[1] + __half2float(self.h[1])) * di + b2a.y;
        o0.z = (acc[2] + __half2float(self.h[2])) * di + b2a.z;
        o0.w = (acc[3] + __half2float(self.h[3])) * di + b2a.w;
        o1.x = (acc[4] + __half2float(self.h[4])) * di + b2b.x;
        o1.y = (acc[5] + __half2float(self.h[5])) * di + b2b.y;
        o1.z = (acc[6] + __half2float(self.h[6])) * di + b2b.z;
        o1.w = (acc[7] + __half2float(self.h[7])) * di + b2b.w;
        float4* op = (float4*)(out + (size_t)d * OUT_F + i * 8);
        op[0] = o0;
        op[1] = o1;
    }
}

// ---------------- launch: 5 dispatches ----------------

extern "C" void kernel_launch(void* const* d_in, const int* in_sizes, int n_in,
                              void* d_out, int out_size, void* d_ws, size_t ws_size,
                              hipStream_t stream) {
    const float* x     = (const float*)d_in[0];
    const int*   ei    = (const int*)d_in[1];
    const float* W1    = (const float*)d_in[2];
    const float* b1    = (const float*)d_in[3];
    const float* gamma = (const float*)d_in[4];
    const float* beta  = (const float*)d_in[5];
    const float* W2    = (const float*)d_in[6];
    const float* b2    = (const float*)d_in[7];
    float* out = (float*)d_out;

    char* ws = (char*)d_ws;
    int*            blkcnt = (int*)           (ws + 0);          //   153,664 B
    int*            rowptr = (int*)           (ws + 154624);     //   200,004 B
    float*          dinv   = (float*)         (ws + 356352);     //   200,000 B
    float*          st2    = (float*)         (ws + 558080);     //    16,384 B
    unsigned int*   bket   = (unsigned int*)  (ws + 574464);     // 3,200,000 B
    unsigned short* ssrc   = (unsigned short*)(ws + 3785728);    // 1,600,000 B
    __half*         h1r    = (__half*)        (ws + 5387264);    // 6,400,000 B (unscaled)
    __half*         agg1h  = (__half*)        (ws + 11787264);   // 6,400,000 B
    __half*         h2p    = (__half*)        (ws + 18187264);   // 4,000,000 B (stride 40, dinv-scaled)
    int*            perm   = (int*)           (ws + 22187264);   //   200,704 B (degree-sorted slots)
    int*            cpre   = (int*)           (ws + 22387968);   //   153,664 B (colpre_g)
    // total ~22.6 MB

    k_bin<<<NBLK, 512, 0, stream>>>(ei, blkcnt, cpre, bket, st2);
    k_mid<<<NBK + NB_G1, 512, 0, stream>>>(blkcnt, cpre, bket, rowptr, dinv, ssrc,
                                           perm, x, W1, h1r);
    k_agg1<<<NB_AG, 256, 0, stream>>>(rowptr, ssrc, dinv, h1r, b1, perm, agg1h, st2);
    k_gemm2<<<NB_MM, 256, 0, stream>>>(agg1h, st2, gamma, beta, W2, dinv, h2p);
    k_agg2<<<NB_AG, 256, 0, stream>>>(rowptr, ssrc, dinv, h2p, b2, perm, out);
}

// Round 17
// 156.201 us; speedup vs baseline: 1.7453x; 1.7453x over previous
//
#include <hip/hip_runtime.h>
#include <hip/hip_fp16.h>

#define N_NODES 50000
#define N_EDGES 800000
#define IN_F    128
#define HID_F   64
#define OUT_F   40

#define EPB   4096                          // edges per sort block
#define NBLK  ((N_EDGES + EPB - 1) / EPB)   // 196 sort blocks
#define NBK   ((N_NODES + 255) / 256)       // 196 buckets (dst >> 8)
#define CAP   6144                          // per-bucket LDS cap (avg 4082, sd 64)
#define NREP  32                            // BN-stat atomic replicas
#define NB_MM ((N_NODES + 63) / 64)         // 782 gemm2 blocks (64 rows each)
#define NB_G1 ((N_NODES + 127) / 128)       // 391 gemm1 blocks (128 rows each)
#define NB_AG ((N_NODES + 31) / 32)         // 1563 agg blocks (32 rows each)

typedef _Float16 half8v __attribute__((ext_vector_type(8)));
typedef float    f32x4  __attribute__((ext_vector_type(4)));

union h8cv { uint4 u; __half h[8]; };

// ============ dispatch 1: binscatter ONLY (196 blocks) ============
// Stores blkcnt AND colpre_g so k_mid's bucket role needs no O(b) prefix loop.

__global__ __launch_bounds__(512) void k_bin(const int* __restrict__ ei,
                                             int* __restrict__ blkcnt,
                                             int* __restrict__ colpre_g,
                                             unsigned int* __restrict__ bket,
                                             float* __restrict__ st2) {
    __shared__ unsigned int staged[EPB];   // 16 KB
    __shared__ int h[256], fill[256];
    __shared__ int wt[4];
    int t = threadIdx.x;
    int lane = t & 63, wv = t >> 6;
    if (t < 256) h[t] = 0;
    if (blockIdx.x == 0)                   // zero BN-stat replicas once
        for (int i = t; i < NREP * 2 * HID_F; i += 512) st2[i] = 0.f;
    __syncthreads();
    int base = blockIdx.x * EPB;
    int nedge = N_EDGES - base; if (nedge > EPB) nedge = EPB;
#pragma unroll
    for (int it = 0; it < EPB / 512; ++it) {
        int e = base + it * 512 + t;
        if (e < N_EDGES) atomicAdd(&h[ei[N_EDGES + e] >> 8], 1);
    }
    __syncthreads();
    // wave shfl scan over h[256] -> exclusive prefix in fill
    int v = (t < 256) ? h[t] : 0;
    int sv = v;
    if (t < 256) {
#pragma unroll
        for (int o = 1; o < 64; o <<= 1) {
            int u = __shfl_up(sv, o);
            if (lane >= o) sv += u;
        }
        if (lane == 63) wt[wv] = sv;
    }
    __syncthreads();
    if (t < 256) {
        int off = 0;
        if (wv > 0) off += wt[0];
        if (wv > 1) off += wt[1];
        if (wv > 2) off += wt[2];
        int ex = sv + off - v;             // exclusive prefix over buckets
        fill[t] = ex;
        if (t < NBK) colpre_g[t * NBLK + blockIdx.x] = ex;   // per-bucket column offset
    }
    __syncthreads();
#pragma unroll
    for (int it = 0; it < EPB / 512; ++it) {
        int e = base + it * 512 + t;
        if (e < N_EDGES) {
            int srcv = ei[e], dstv = ei[N_EDGES + e];
            int p = atomicAdd(&fill[dstv >> 8], 1);
            staged[p] = ((unsigned int)dstv << 16) | (unsigned int)srcv;
        }
    }
    __syncthreads();
    for (int i = t; i < nedge; i += 512) bket[base + i] = staged[i];
    if (t < NBK) blkcnt[t * NBLK + blockIdx.x] = h[t];
}

// ============ dispatch 2: bucket CSR build (blocks 0..195) || gemm1 (rest) ============

__global__ __launch_bounds__(512) void k_mid(const int* __restrict__ blkcnt,
                                             const int* __restrict__ colpre_g,
                                             const unsigned int* __restrict__ bket,
                                             int* __restrict__ rowptr,
                                             float* __restrict__ dinv,
                                             unsigned short* __restrict__ ssrc,
                                             int* __restrict__ perm,
                                             const float* __restrict__ x,
                                             const float* __restrict__ W1,
                                             __half* __restrict__ h1r) {
    __shared__ uint4 pool[3328];           // 53248 B shared pool (both roles)
    __shared__ int colpre[256], rowcnt[256], boffs[256];
    __shared__ int cnt[256], fillb[256];
    __shared__ int wt[4], wsum[8], sbase, ssize;
    __shared__ int dbin[64], dfl[64];
    int t = threadIdx.x;
    int lane = t & 63, wid = t >> 6;

    if (blockIdx.x < NBK) {
        // ---------------- bucket role ----------------
        unsigned int*   keys = (unsigned int*)pool;                    // 24576 B
        unsigned short* outb = (unsigned short*)((char*)pool + 24576); // 12288 B
        int b = blockIdx.x;

        int cp = 0, rc = 0;
        if (t < NBLK) {
            cp = colpre_g[b * NBLK + t];   // one coalesced load (was O(b) loop)
            rc = blkcnt[b * NBLK + t];
        }
        if (t < 256) { colpre[t] = cp; rowcnt[t] = rc; }
        int red = cp;
#pragma unroll
        for (int o = 32; o > 0; o >>= 1) red += __shfl_down(red, o);
        if (lane == 0) wsum[wid] = red;
        int sv = rc;
        if (t < 256) {
#pragma unroll
            for (int o = 1; o < 64; o <<= 1) {
                int u = __shfl_up(sv, o);
                if (lane >= o) sv += u;
            }
            if (lane == 63) wt[wid] = sv;
        }
        __syncthreads();
        if (t == 0) {
            int s = 0;
#pragma unroll
            for (int r = 0; r < 8; ++r) s += wsum[r];
            sbase = s;
        }
        if (t < 256) {
            int off = 0;
            if (wid > 0) off += wt[0];
            if (wid > 1) off += wt[1];
            if (wid > 2) off += wt[2];
            boffs[t] = sv + off - rc;
            if (t == 255) ssize = sv + off;
        }
        __syncthreads();
        int base = sbase, size = ssize;

        // 32-lane half-wave per segment: 2x segment streams, better lane use
        int hw = t >> 5, hl = t & 31;      // hw 0..15
        for (int jj = hw; jj < NBLK; jj += 16) {
            int len = rowcnt[jj];
            int gs  = jj * EPB + colpre[jj];
            int d0  = boffs[jj];
            for (int o = hl; o < len; o += 32) keys[d0 + o] = bket[gs + o];
        }
        if (t < 256) cnt[t] = 0;
        __syncthreads();

        for (int i = t; i < size; i += 512) atomicAdd(&cnt[(keys[i] >> 16) & 255], 1);
        __syncthreads();
        int cv = (t < 256) ? cnt[t] : 0;
        int sv2 = cv;
        if (t < 256) {
#pragma unroll
            for (int o = 1; o < 64; o <<= 1) {
                int u = __shfl_up(sv2, o);
                if (lane >= o) sv2 += u;
            }
            if (lane == 63) wt[wid] = sv2;
        }
        __syncthreads();
        if (t < 256) {
            int off = 0;
            if (wid > 0) off += wt[0];
            if (wid > 1) off += wt[1];
            if (wid > 2) off += wt[2];
            int ex = sv2 + off - cv;
            fillb[t] = ex;
            int node = b * 256 + t;
            if (node < N_NODES) {
                rowptr[node] = base + ex;
                dinv[node]   = rsqrtf((float)cv + 1.0f);   // + self-loop
            }
        }
        if (b == 0 && t == 0) rowptr[N_NODES] = N_EDGES;
        __syncthreads();

        for (int i = t; i < size; i += 512) {
            unsigned int k = keys[i];
            int p = atomicAdd(&fillb[(k >> 16) & 255], 1);
            outb[p] = (unsigned short)(k & 0xFFFFu);
        }
        __syncthreads();
        for (int i = t; i < size; i += 512) ssrc[base + i] = outb[i];

        // ---- degree-sort this bucket's 256 slots -> perm ----
        if (t < 64) dbin[t] = 0;
        __syncthreads();
        int node2 = b * 256 + t;
        int dg = 63;
        if (t < 256) {
            if (node2 < N_NODES) { dg = cv; if (dg > 62) dg = 62; }
            atomicAdd(&dbin[dg], 1);
        }
        __syncthreads();
        if (t < 64) {                       // one full wave: exclusive scan of 64 bins
            int bv = dbin[t];
            int s = bv;
#pragma unroll
            for (int o = 1; o < 64; o <<= 1) {
                int u = __shfl_up(s, o);
                if (lane >= o) s += u;
            }
            dfl[t] = s - bv;                // exclusive
        }
        __syncthreads();
        if (t < 256) {
            int r = atomicAdd(&dfl[dg], 1);
            perm[b * 256 + r] = node2;      // invalid ids sort last
        }
        return;
    }

    // ---------------- gemm1 role: 128 rows, MFMA 16x16x32 f16 ----------------
    _Float16 (*sA)[IN_F + 8] = (_Float16(*)[IN_F + 8])pool;                    // 34816 B
    _Float16 (*sB)[IN_F + 8] = (_Float16(*)[IN_F + 8])((char*)pool + 34816);   // 17408 B
    int bid = blockIdx.x - NBK;
    int row0 = bid * 128;
    for (int i = t; i < 128 * 32; i += 512) {
        int r  = i >> 5;
        int c4 = i & 31;
        int gr = row0 + r;
        float4 v = make_float4(0.f, 0.f, 0.f, 0.f);
        if (gr < N_NODES) v = ((const float4*)x)[gr * 32 + c4];
        sA[r][c4 * 4 + 0] = (_Float16)v.x;
        sA[r][c4 * 4 + 1] = (_Float16)v.y;
        sA[r][c4 * 4 + 2] = (_Float16)v.z;
        sA[r][c4 * 4 + 3] = (_Float16)v.w;
    }
    for (int i = t; i < IN_F * HID_F; i += 512) {
        int k = i >> 6, n = i & 63;
        sB[n][k] = (_Float16)W1[i];
    }
    __syncthreads();

    int quad = lane >> 4, l15 = lane & 15;
    int m0 = wid * 16;
    half8v af[4];
#pragma unroll
    for (int ks = 0; ks < 4; ++ks)
        af[ks] = *(const half8v*)&sA[m0 + l15][ks * 32 + quad * 8];
    f32x4 acc[4];
#pragma unroll
    for (int nt = 0; nt < 4; ++nt) acc[nt] = (f32x4)(0.f);
#pragma unroll
    for (int nt = 0; nt < 4; ++nt) {
#pragma unroll
        for (int ks = 0; ks < 4; ++ks) {
            half8v bf = *(const half8v*)&sB[nt * 16 + l15][ks * 32 + quad * 8];
            acc[nt] = __builtin_amdgcn_mfma_f32_16x16x32_f16(af[ks], bf, acc[nt], 0, 0, 0);
        }
    }
    int rbase = row0 + m0 + quad * 4;
#pragma unroll
    for (int nt = 0; nt < 4; ++nt) {
        int col = nt * 16 + l15;
#pragma unroll
        for (int r = 0; r < 4; ++r) {
            int gr = rbase + r;
            if (gr < N_NODES)
                h1r[gr * HID_F + col] = __float2half(acc[nt][r]);   // unscaled
        }
    }
}

// ============ dispatch 3: layer-1 aggregation + BN stats ============
// ONE 8-LANE GROUP PER ROW via perm. dinv gathered ONCE per edge (own lane,
// overlapped with ssrc load) and redistributed via shuffle. 4-deep gather
// batches at LB(256,8) = the constrained optimum (R13/R16 bracketed it).

__global__ __launch_bounds__(256, 8) void k_agg1(const int* __restrict__ rowptr,
                                                 const unsigned short* __restrict__ ssrc,
                                                 const float* __restrict__ dinv,
                                                 const __half* __restrict__ h1r,
                                                 const float* __restrict__ b1,
                                                 const int* __restrict__ perm,
                                                 __half* __restrict__ agg1h,
                                                 float* __restrict__ st2) {
    __shared__ float vs[32][HID_F + 1];    // 8448 B staged vals for BN reduce
    int t = threadIdx.x;
    int lane = t & 63, wid = t >> 6;
    int g = lane >> 3, i = lane & 7;
    int rloc = wid * 8 + g;                // 0..31
    int d = perm[blockIdx.x * 32 + rloc];  // degree-sorted row id
    bool valid = d < N_NODES;
    int base = 0, end = 0;
    if (valid) { base = rowptr[d]; end = rowptr[d + 1]; }
    float acc[8];
#pragma unroll
    for (int c = 0; c < 8; ++c) acc[c] = 0.f;

    for (int cc = base; cc < end; cc += 8) {
        int nrem = end - cc; if (nrem > 8) nrem = 8;
        int e = 0; float dv_own = 0.f;
        if (i < nrem) {
            e = (int)ssrc[cc + i];
            dv_own = dinv[e];              // own-edge weight, issued early
        }
#pragma unroll
        for (int kb = 0; kb < 8; kb += 4) {
            if (kb < nrem) {
                int sk[4]; float w[4]; uint4 v[4];
#pragma unroll
                for (int k = 0; k < 4; ++k) {
                    sk[k] = __shfl(e,      (lane & 56) + kb + k);   // within own group
                    w[k]  = __shfl(dv_own, (lane & 56) + kb + k);   // weight rides along
                }
#pragma unroll
                for (int k = 0; k < 4; ++k) {
                    if (kb + k < nrem)                              // group-uniform
                        v[k] = ((const uint4*)(h1r + (size_t)sk[k] * HID_F))[i];
                    else v[k] = make_uint4(0, 0, 0, 0);
                }
#pragma unroll
                for (int k = 0; k < 4; ++k) {
                    float wk = (kb + k < nrem) ? w[k] : 0.f;
                    h8cv cv; cv.u = v[k];
#pragma unroll
                    for (int c = 0; c < 8; ++c)
                        acc[c] += wk * __half2float(cv.h[c]);
                }
            }
        }
    }

    float val[8];
    if (valid) {
        float di = dinv[d];
        h8cv self; self.u = ((const uint4*)(h1r + (size_t)d * HID_F))[i];
        const float4 b1a = ((const float4*)b1)[i * 2];
        const float4 b1b = ((const float4*)b1)[i * 2 + 1];
        val[0] = (acc[0] + di * __half2float(self.h[0])) * di + b1a.x;
        val[1] = (acc[1] + di * __half2float(self.h[1])) * di + b1a.y;
        val[2] = (acc[2] + di * __half2float(self.h[2])) * di + b1a.z;
        val[3] = (acc[3] + di * __half2float(self.h[3])) * di + b1a.w;
        val[4] = (acc[4] + di * __half2float(self.h[4])) * di + b1b.x;
        val[5] = (acc[5] + di * __half2float(self.h[5])) * di + b1b.y;
        val[6] = (acc[6] + di * __half2float(self.h[6])) * di + b1b.z;
        val[7] = (acc[7] + di * __half2float(self.h[7])) * di + b1b.w;
        h8cv ov;
#pragma unroll
        for (int c = 0; c < 8; ++c) ov.h[c] = __float2half(val[c]);
        ((uint4*)(agg1h + (size_t)d * HID_F))[i] = ov.u;
    } else {
#pragma unroll
        for (int c = 0; c < 8; ++c) val[c] = 0.f;
    }
#pragma unroll
    for (int c = 0; c < 8; ++c) vs[rloc][i * 8 + c] = val[c];
    __syncthreads();
    if (t < HID_F) {
        float sm = 0.f, s2 = 0.f;
#pragma unroll 4
        for (int r = 0; r < 32; ++r) {
            float v2 = vs[r][t];
            sm += v2; s2 += v2 * v2;
        }
        float* strow = st2 + (blockIdx.x & (NREP - 1)) * (2 * HID_F);
        atomicAdd(&strow[t], sm);
        atomicAdd(&strow[HID_F + t], s2);
    }
}

// ============ dispatch 4: GEMM2 (MFMA), h2p[N,40] pre-scaled by dinv ============

__global__ __launch_bounds__(256) void k_gemm2(const __half* __restrict__ agg1h,
                                               const float* __restrict__ st2,
                                               const float* __restrict__ gamma,
                                               const float* __restrict__ beta,
                                               const float* __restrict__ W2,
                                               const float* __restrict__ dinv,
                                               __half* __restrict__ h2p) {
    __shared__ _Float16 sA[64][HID_F + 8];   // 9216 B
    __shared__ _Float16 sB[48][HID_F + 8];   // 6912 B  (sB[n][k] = W2[k][n], pad n>=40)
    __shared__ float sScale[HID_F], sShift[HID_F];
    int t = threadIdx.x;
    if (t < HID_F) {
        float sm = 0.f, s2 = 0.f;
#pragma unroll
        for (int r = 0; r < NREP; ++r) {
            sm += st2[r * (2 * HID_F) + t];
            s2 += st2[r * (2 * HID_F) + HID_F + t];
        }
        float mean = sm * (1.0f / N_NODES);
        float var  = s2 * (1.0f / N_NODES) - mean * mean;
        float inv  = rsqrtf(var + 1e-5f);
        float gv   = gamma[t];
        sScale[t]  = gv * inv;
        sShift[t]  = beta[t] - gv * inv * mean;
    }
    for (int i = t; i < 48 * HID_F; i += 256) {
        int k = i / 48, n = i - k * 48;
        sB[n][k] = (n < OUT_F) ? (_Float16)W2[k * OUT_F + n] : (_Float16)0.f;
    }
    __syncthreads();
    int row0 = blockIdx.x * 64;
    for (int i = t; i < 64 * HID_F; i += 256) {
        int r = i >> 6, k = i & 63;
        int gr = row0 + r;
        float v = 0.f;
        if (gr < N_NODES) {
            float a = __half2float(agg1h[gr * HID_F + k]);
            v = fmaxf(a * sScale[k] + sShift[k], 0.f);
        }
        sA[r][k] = (_Float16)v;
    }
    __syncthreads();

    int lane = t & 63, wid = t >> 6;
    int quad = lane >> 4, l15 = lane & 15;
    int m0 = wid * 16;
    half8v af[2];
#pragma unroll
    for (int ks = 0; ks < 2; ++ks)
        af[ks] = *(const half8v*)&sA[m0 + l15][ks * 32 + quad * 8];
    f32x4 acc[3];
#pragma unroll
    for (int nt = 0; nt < 3; ++nt) acc[nt] = (f32x4)(0.f);
#pragma unroll
    for (int nt = 0; nt < 3; ++nt) {
#pragma unroll
        for (int ks = 0; ks < 2; ++ks) {
            half8v bf = *(const half8v*)&sB[nt * 16 + l15][ks * 32 + quad * 8];
            acc[nt] = __builtin_amdgcn_mfma_f32_16x16x32_f16(af[ks], bf, acc[nt], 0, 0, 0);
        }
    }
    float dv[4];
    int rbase = row0 + m0 + quad * 4;
#pragma unroll
    for (int r = 0; r < 4; ++r)
        dv[r] = (rbase + r < N_NODES) ? dinv[rbase + r] : 0.f;
#pragma unroll
    for (int nt = 0; nt < 3; ++nt) {
        int col = nt * 16 + l15;
        if (col < OUT_F) {
#pragma unroll
            for (int r = 0; r < 4; ++r) {
                int gr = rbase + r;
                if (gr < N_NODES)
                    h2p[(size_t)gr * OUT_F + col] = __float2half(acc[nt][r] * dv[r]);
            }
        }
    }
}

// ============ dispatch 5: layer-2 aggregation -> d_out ============
// ONE 8-LANE GROUP PER ROW via perm; LB(256,8); lanes i<5 gather (80 B rows).

__global__ __launch_bounds__(256, 8) void k_agg2(const int* __restrict__ rowptr,
                                                 const unsigned short* __restrict__ ssrc,
                                                 const float* __restrict__ dinv,
                                                 const __half* __restrict__ h2p,
                                                 const float* __restrict__ b2,
                                                 const int* __restrict__ perm,
                                                 float* __restrict__ out) {
    int t = threadIdx.x;
    int lane = t & 63, wid = t >> 6;
    int g = lane >> 3, i = lane & 7;
    int rloc = wid * 8 + g;
    int d = perm[blockIdx.x * 32 + rloc];  // degree-sorted row id
    bool valid = d < N_NODES;
    int base = 0, end = 0;
    if (valid) { base = rowptr[d]; end = rowptr[d + 1]; }
    float acc[8];
#pragma unroll
    for (int c = 0; c < 8; ++c) acc[c] = 0.f;

    for (int cc = base; cc < end; cc += 8) {
        int nrem = end - cc; if (nrem > 8) nrem = 8;
        int e = (i < nrem) ? (int)ssrc[cc + i] : 0;
#pragma unroll
        for (int kb = 0; kb < 8; kb += 4) {
            if (kb < nrem) {
                int sk[4];
#pragma unroll
                for (int k = 0; k < 4; ++k)
                    sk[k] = __shfl(e, (lane & 56) + kb + k);   // all lanes shuffle
                if (i < 5) {
                    uint4 v[4];
#pragma unroll
                    for (int k = 0; k < 4; ++k) {
                        if (kb + k < nrem)
                            v[k] = ((const uint4*)(h2p + (size_t)sk[k] * OUT_F))[i];
                        else v[k] = make_uint4(0, 0, 0, 0);
                    }
#pragma unroll
                    for (int k = 0; k < 4; ++k) {
                        h8cv cv; cv.u = v[k];
#pragma unroll
                        for (int c = 0; c < 8; ++c)
                            acc[c] += __half2float(cv.h[c]);
                    }
                }
            }
        }
    }

    if (valid && i < 5) {
        h8cv self; self.u = ((const uint4*)(h2p + (size_t)d * OUT_F))[i];
        float di = dinv[d];
        const float4 b2a = ((const float4*)b2)[i * 2];
        const float4 b2b = ((const float4*)b2)[i * 2 + 1];
        float4 o0, o1;
        o0.x = (acc[0] + __half2float(self.h[0])) * di + b2a.x;
        o0.y = (acc[1] + __half2float(self.h[1])) * di + b2a.y;
        o0.z = (acc[2] + __half2float(self.h[2])) * di + b2a.z;
        o0.w = (acc[3] + __half2float(self.h[3])) * di + b2a.w;
        o1.x = (acc[4] + __half2float(self.h[4])) * di + b2b.x;
        o1.y = (acc[5] + __half2float(self.h[5])) * di + b2b.y;
        o1.z = (acc[6] + __half2float(self.h[6])) * di + b2b.z;
        o1.w = (acc[7] + __half2float(self.h[7])) * di + b2b.w;
        float4* op = (float4*)(out + (size_t)d * OUT_F + i * 8);
        op[0] = o0;
        op[1] = o1;
    }
}

// ---------------- launch: 5 dispatches ----------------

extern "C" void kernel_launch(void* const* d_in, const int* in_sizes, int n_in,
                              void* d_out, int out_size, void* d_ws, size_t ws_size,
                              hipStream_t stream) {
    const float* x     = (const float*)d_in[0];
    const int*   ei    = (const int*)d_in[1];
    const float* W1    = (const float*)d_in[2];
    const float* b1    = (const float*)d_in[3];
    const float* gamma = (const float*)d_in[4];
    const float* beta  = (const float*)d_in[5];
    const float* W2    = (const float*)d_in[6];
    const float* b2    = (const float*)d_in[7];
    float* out = (float*)d_out;

    char* ws = (char*)d_ws;
    int*            blkcnt = (int*)           (ws + 0);          //   153,664 B
    int*            rowptr = (int*)           (ws + 154624);     //   200,004 B
    float*          dinv   = (float*)         (ws + 356352);     //   200,000 B
    float*          st2    = (float*)         (ws + 558080);     //    16,384 B
    unsigned int*   bket   = (unsigned int*)  (ws + 574464);     // 3,200,000 B
    unsigned short* ssrc   = (unsigned short*)(ws + 3785728);    // 1,600,000 B
    __half*         h1r    = (__half*)        (ws + 5387264);    // 6,400,000 B (unscaled)
    __half*         agg1h  = (__half*)        (ws + 11787264);   // 6,400,000 B
    __half*         h2p    = (__half*)        (ws + 18187264);   // 4,000,000 B (stride 40, dinv-scaled)
    int*            perm   = (int*)           (ws + 22187264);   //   200,704 B (degree-sorted slots)
    int*            cpre   = (int*)           (ws + 22387968);   //   153,664 B (colpre_g)
    // total ~22.6 MB

    k_bin<<<NBLK, 512, 0, stream>>>(ei, blkcnt, cpre, bket, st2);
    k_mid<<<NBK + NB_G1, 512, 0, stream>>>(blkcnt, cpre, bket, rowptr, dinv, ssrc,
                                           perm, x, W1, h1r);
    k_agg1<<<NB_AG, 256, 0, stream>>>(rowptr, ssrc, dinv, h1r, b1, perm, agg1h, st2);
    k_gemm2<<<NB_MM, 256, 0, stream>>>(agg1h, st2, gamma, beta, W2, dinv, h2p);
    k_agg2<<<NB_AG, 256, 0, stream>>>(rowptr, ssrc, dinv, h2p, b2, perm, out);
}